// Round 8
// baseline (267.636 us; speedup 1.0000x reference)
//
#include <hip/hip_runtime.h>

#define OUTHALF 8388608
#define CPAD    320
#define MARGIN  7.5e-4f
#define CAP     24

typedef float f32x4 __attribute__((ext_vector_type(4)));
typedef short bf16x8 __attribute__((ext_vector_type(8)));

__device__ __forceinline__ unsigned short f2bf(float x) {   // RNE fp32 -> bf16
    unsigned u = __float_as_uint(x);
    return (unsigned short)((u + 0x7FFFu + ((u >> 16) & 1u)) >> 16);
}
__device__ __forceinline__ unsigned fkey(float f) {         // order-preserving f32->u32
    unsigned b = __float_as_uint(f);
    return b ^ ((b & 0x80000000u) ? 0xFFFFFFFFu : 0x80000000u);
}
__device__ __forceinline__ float finv(unsigned k) {
    unsigned b = k ^ ((k & 0x80000000u) ? 0x80000000u : 0xFFFFFFFFu);
    return __uint_as_float(b);
}
__device__ __forceinline__ void atomicMinU64(unsigned long long* p, unsigned long long v) {
    unsigned long long cur = *p;
    while (v < cur) {
        unsigned long long old = atomicCAS(p, cur, v);
        if (old == cur) break;
        cur = old;
    }
}

// ---- kernel A1: zplane (bf16 [32768][320], slot256=1.0) + exact z2 ----
__global__ __launch_bounds__(256) void prep_z(const float* __restrict__ z,
                                              float* __restrict__ out) {
    __shared__ float tile[64][65];
    const int t = threadIdx.x;
    const int n0 = blockIdx.x * 64;
    const int b = n0 >> 10, hw0 = n0 & 1023;
    const float* zb = z + (size_t)b * 262144 + hw0;
    unsigned short* zpl = (unsigned short*)out;

    for (int ch = 0; ch < 4; ++ch) {
        __syncthreads();
        #pragma unroll
        for (int r = 0; r < 16; ++r) {
            int c = r * 4 + (t >> 6);
            int nn = t & 63;
            tile[c][nn] = zb[(size_t)(ch * 64 + c) * 1024 + nn];
        }
        __syncthreads();
        #pragma unroll
        for (int i = 0; i < 2; ++i) {
            int id = i * 256 + t;
            int row = id >> 3, seg = id & 7;
            unsigned short tmp[8];
            #pragma unroll
            for (int j = 0; j < 8; ++j) tmp[j] = f2bf(tile[seg * 8 + j][row]);
            *(uint4*)(zpl + (size_t)(n0 + row) * CPAD + ch * 64 + seg * 8) = *(const uint4*)tmp;
        }
    }
    if (t < 64) {
        const float* p = zb + t;
        float s = 0.0f;
        #pragma unroll 8
        for (int c = 0; c < 256; ++c) { float v = p[(size_t)c * 1024]; s = fmaf(v, v, s); }
        ((float*)(out + OUTHALF + 262144))[n0 + t] = s;   // exact z2
        unsigned short* rowp = zpl + (size_t)(n0 + t) * CPAD + 256;
        rowp[0] = 0x3F80;                                  // bf16(1.0)
        for (int j = 1; j < 64; ++j) rowp[j] = 0;
    }
}

// ---- kernel A2: wplane (bf16 [1024][320], slot256=bf16(-w2/2)) + exact w2 ----
__global__ __launch_bounds__(256) void prep_w(const float* __restrict__ w,
                                              float* __restrict__ out) {
    const int k = blockIdx.x * 256 + threadIdx.x;
    if (k >= 1024) return;
    unsigned short* wpl = (unsigned short*)(out + OUTHALF);
    const float4* row = (const float4*)(w + (size_t)k * 256);
    float s = 0.0f;
    #pragma unroll 4
    for (int c4 = 0; c4 < 64; ++c4) {
        float4 v = row[c4];
        s += v.x * v.x;
        s += v.y * v.y;
        s += v.z * v.z;
        s += v.w * v.w;
        unsigned short t4[4] = {f2bf(v.x), f2bf(v.y), f2bf(v.z), f2bf(v.w)};
        *(uint2*)(wpl + (size_t)k * CPAD + c4 * 4) = *(const uint2*)t4;
    }
    ((float*)(out + OUTHALF + 262144 + 32768))[k] = s;     // exact w2
    unsigned short* rowp = wpl + (size_t)k * CPAD + 256;
    rowp[0] = f2bf(-0.5f * s);
    for (int j = 1; j < 64; ++j) rowp[j] = 0;
}

// ---- kernel B: MFMA approx scores + candidate collection + exact recheck ----
__global__ __launch_bounds__(256) void vq_main(const float* __restrict__ z,
                                               const float* __restrict__ w,
                                               float* __restrict__ out) {
    __shared__ uint4 ztb[128 * 9];          // 128 n-rows x 144 B (64c bf16 + pad)
    __shared__ unsigned rmink[128];
    __shared__ unsigned cnt[128];
    __shared__ unsigned candk[128 * CAP];
    __shared__ unsigned long long best[128];
    __shared__ unsigned short ovlist[128];
    __shared__ unsigned ovcnt;

    const int t = threadIdx.x;
    const int lane = t & 63;
    const int wid = t >> 6;
    const int n0 = blockIdx.x * 128;
    const int l15 = lane & 15;
    const int lq  = lane >> 4;

    const unsigned short* zpl = (const unsigned short*)out;
    const unsigned short* wpl = (const unsigned short*)(out + OUTHALF);
    const float* z2arr = (const float*)(out + OUTHALF + 262144);
    const float* w2arr = (const float*)(out + OUTHALF + 262144 + 32768);

    for (int i = t; i < 128; i += 256) {
        rmink[i] = 0xFF7FFFFFu;             // fkey(FLT_MAX)
        cnt[i] = 0;
        best[i] = ~0ull;
    }
    if (t == 0) ovcnt = 0;

    #pragma unroll 1
    for (int pass = 0; pass < 8; ++pass) {
        const int kbase = pass * 128 + wid * 32;
        f32x4 acc[2][8];
        #pragma unroll
        for (int kt = 0; kt < 2; ++kt)
            #pragma unroll
            for (int sub = 0; sub < 8; ++sub) acc[kt][sub] = 0.0f;

        #pragma unroll 1
        for (int chunk = 0; chunk < 5; ++chunk) {
            __syncthreads();
            #pragma unroll
            for (int i = 0; i < 4; ++i) {
                int id = i * 256 + t;
                int row = id >> 3, seg = id & 7;
                ztb[row * 9 + seg] =
                    *(const uint4*)(zpl + (size_t)(n0 + row) * CPAD + chunk * 64 + seg * 8);
            }
            __syncthreads();
            #pragma unroll
            for (int step = 0; step < 2; ++step) {
                const int cs = chunk * 64 + step * 32;
                bf16x8 afr[2];
                #pragma unroll
                for (int kt = 0; kt < 2; ++kt) {
                    int rowk = kbase + kt * 16 + l15;
                    afr[kt] = *(const bf16x8*)(wpl + (size_t)rowk * CPAD + cs + lq * 8);
                }
                #pragma unroll
                for (int sub = 0; sub < 8; ++sub) {
                    int n = sub * 16 + l15;
                    bf16x8 bfr = *(const bf16x8*)((const unsigned short*)ztb + n * 72 + step * 32 + lq * 8);
                    #pragma unroll
                    for (int kt = 0; kt < 2; ++kt)
                        acc[kt][sub] = __builtin_amdgcn_mfma_f32_16x16x32_bf16(
                            afr[kt], bfr, acc[kt][sub], 0, 0, 0);
                }
            }
        }
        // finalize pass (a): settle per-n running min
        #pragma unroll
        for (int sub = 0; sub < 8; ++sub) {
            int n = sub * 16 + l15;
            float m = 3.4e38f;
            #pragma unroll
            for (int kt = 0; kt < 2; ++kt)
                #pragma unroll
                for (int r = 0; r < 4; ++r) m = fminf(m, -2.0f * acc[kt][sub][r]);
            atomicMin(&rmink[n], fkey(m));
        }
        __syncthreads();
        // finalize pass (c): append all k within margin of settled min
        #pragma unroll
        for (int sub = 0; sub < 8; ++sub) {
            int n = sub * 16 + l15;
            float thr = finv(rmink[n]) + MARGIN;
            #pragma unroll
            for (int kt = 0; kt < 2; ++kt)
                #pragma unroll
                for (int r = 0; r < 4; ++r) {
                    float s = -2.0f * acc[kt][sub][r];
                    if (s <= thr) {
                        unsigned slot = atomicAdd(&cnt[n], 1u);
                        if (slot < CAP) candk[n * CAP + slot] = (unsigned)(kbase + kt * 16 + lq * 4 + r);
                    }
                }
        }
        __syncthreads();
    }

    // overflow list
    if (t < 128 && cnt[t] > CAP) {
        unsigned o = atomicAdd(&ovcnt, 1u);
        ovlist[o] = (unsigned short)t;
    }
    // exact recheck of candidates (reference chain: sequential-c fmaf, first-index ties)
    #pragma unroll 1
    for (int p = t; p < 128 * CAP; p += 256) {
        int nl = p / CAP, slot = p % CAP;
        unsigned c_ = cnt[nl];
        if (c_ > CAP || slot >= (int)c_) continue;
        unsigned k = candk[p];
        int n = n0 + nl;
        const float* zc = z + (size_t)(n >> 10) * 262144 + (n & 1023);
        const float* wr = w + (size_t)k * 256;
        float s = 0.0f;
        #pragma unroll 8
        for (int c = 0; c < 256; ++c) s = fmaf(zc[(size_t)c * 1024], wr[c], s);
        float d = fmaf(-2.0f, s, z2arr[n]) + w2arr[k];
        atomicMinU64(&best[nl], ((unsigned long long)__float_as_uint(d) << 32) | k);
    }
    __syncthreads();
    // rare fallback: full exact scan for overflowed n (one wave per n)
    for (unsigned o = wid; o < ovcnt; o += 4) {
        int nl = ovlist[o];
        int n = n0 + nl;
        const float* zc = z + (size_t)(n >> 10) * 262144 + (n & 1023);
        unsigned long long m = ~0ull;
        for (int kk = lane; kk < 1024; kk += 64) {
            const float* wr = w + (size_t)kk * 256;
            float s = 0.0f;
            #pragma unroll 8
            for (int c = 0; c < 256; ++c) s = fmaf(zc[(size_t)c * 1024], wr[c], s);
            float d = fmaf(-2.0f, s, z2arr[n]) + w2arr[kk];
            unsigned long long key = ((unsigned long long)__float_as_uint(d) << 32) | (unsigned)kk;
            m = (key < m) ? key : m;
        }
        #pragma unroll
        for (int sh = 1; sh <= 32; sh <<= 1) {
            unsigned long long o2 = __shfl_xor(m, sh, 64);
            m = (o2 < m) ? o2 : m;
        }
        if (lane == 0) atomicMinU64(&best[nl], m);
    }
    __syncthreads();
    if (t < 128) out[(size_t)2 * OUTHALF + n0 + t] = (float)(unsigned)(best[t] & 0xFFFFFFFFu);
}

// ---- kernel C: gather + write code/detached (round-5 proven epilogue) ----
__global__ __launch_bounds__(256) void epilogue(const float* __restrict__ z,
                                                const float* __restrict__ w,
                                                float* __restrict__ out) {
    const int t = threadIdx.x;
    const int n0 = blockIdx.x * 32;
    const int b = n0 >> 10, hw0 = n0 & 1023;
    const int n = t & 31;
    const int q = t >> 5;
    const int kn = (int)out[(size_t)2 * OUTHALF + n0 + n];
    const float* wrow = w + (size_t)kn * 256;
    const size_t obase = (size_t)b * 262144 + hw0;
    #pragma unroll
    for (int cc = 0; cc < 8; ++cc) {
        const int c0 = (q + cc * 8) * 4;
        const float4 cv = *(const float4*)(wrow + c0);
        const float cvf[4] = {cv.x, cv.y, cv.z, cv.w};
        #pragma unroll
        for (int u = 0; u < 4; ++u) {
            const size_t off = obase + (size_t)(c0 + u) * 1024 + n;
            const float zz = z[off];
            out[off] = cvf[u];
            out[OUTHALF + off] = (cvf[u] - zz) + zz;   // reference rounding chain
        }
    }
}

extern "C" void kernel_launch(void* const* d_in, const int* in_sizes, int n_in,
                              void* d_out, int out_size, void* d_ws, size_t ws_size,
                              hipStream_t stream) {
    const float* z = (const float*)d_in[0];
    const float* w = (const float*)d_in[1];
    float* out = (float*)d_out;
    prep_z  <<<512, 256, 0, stream>>>(z, out);
    prep_w  <<<4,   256, 0, stream>>>(w, out);
    vq_main <<<256, 256, 0, stream>>>(z, w, out);
    epilogue<<<1024, 256, 0, stream>>>(z, w, out);
}

// Round 9
// 265.804 us; speedup vs baseline: 1.0069x; 1.0069x over previous
//
#include <hip/hip_runtime.h>

#define OUTHALF 8388608
#define CPAD    320
#define MARGIN  7.5e-4f
#define CAP     24

typedef float f32x4 __attribute__((ext_vector_type(4)));
typedef short bf16x8 __attribute__((ext_vector_type(8)));

__device__ __forceinline__ unsigned short f2bf(float x) {   // RNE fp32 -> bf16
    unsigned u = __float_as_uint(x);
    return (unsigned short)((u + 0x7FFFu + ((u >> 16) & 1u)) >> 16);
}
__device__ __forceinline__ unsigned fkey(float f) {         // order-preserving f32->u32
    unsigned b = __float_as_uint(f);
    return b ^ ((b & 0x80000000u) ? 0xFFFFFFFFu : 0x80000000u);
}
__device__ __forceinline__ float finv(unsigned k) {
    unsigned b = k ^ ((k & 0x80000000u) ? 0x80000000u : 0xFFFFFFFFu);
    return __uint_as_float(b);
}
__device__ __forceinline__ void atomicMinU64(unsigned long long* p, unsigned long long v) {
    unsigned long long cur = *p;
    while (v < cur) {
        unsigned long long old = atomicCAS(p, cur, v);
        if (old == cur) break;
        cur = old;
    }
}

// ---- kernel A1: zplane (bf16 [32768][320], slot256=1.0) + exact z2 ----
__global__ __launch_bounds__(256) void prep_z(const float* __restrict__ z,
                                              float* __restrict__ out) {
    __shared__ float tile[64][65];
    const int t = threadIdx.x;
    const int n0 = blockIdx.x * 64;
    const int b = n0 >> 10, hw0 = n0 & 1023;
    const float* zb = z + (size_t)b * 262144 + hw0;
    unsigned short* zpl = (unsigned short*)out;

    for (int ch = 0; ch < 4; ++ch) {
        __syncthreads();
        #pragma unroll
        for (int r = 0; r < 16; ++r) {
            int c = r * 4 + (t >> 6);
            int nn = t & 63;
            tile[c][nn] = zb[(size_t)(ch * 64 + c) * 1024 + nn];
        }
        __syncthreads();
        #pragma unroll
        for (int i = 0; i < 2; ++i) {
            int id = i * 256 + t;
            int row = id >> 3, seg = id & 7;
            unsigned short tmp[8];
            #pragma unroll
            for (int j = 0; j < 8; ++j) tmp[j] = f2bf(tile[seg * 8 + j][row]);
            *(uint4*)(zpl + (size_t)(n0 + row) * CPAD + ch * 64 + seg * 8) = *(const uint4*)tmp;
        }
    }
    if (t < 64) {
        const float* p = zb + t;
        float s = 0.0f;
        #pragma unroll 8
        for (int c = 0; c < 256; ++c) { float v = p[(size_t)c * 1024]; s = fmaf(v, v, s); }
        ((float*)(out + OUTHALF + 262144))[n0 + t] = s;   // exact z2
        unsigned short* rowp = zpl + (size_t)(n0 + t) * CPAD + 256;
        rowp[0] = 0x3F80;                                  // bf16(1.0)
        for (int j = 1; j < 64; ++j) rowp[j] = 0;
    }
}

// ---- kernel A2: wplane (bf16 [1024][320], slot256=bf16(-w2/2)) + exact w2 ----
__global__ __launch_bounds__(256) void prep_w(const float* __restrict__ w,
                                              float* __restrict__ out) {
    const int k = blockIdx.x * 256 + threadIdx.x;
    if (k >= 1024) return;
    unsigned short* wpl = (unsigned short*)(out + OUTHALF);
    const float4* row = (const float4*)(w + (size_t)k * 256);
    float s = 0.0f;
    #pragma unroll 4
    for (int c4 = 0; c4 < 64; ++c4) {
        float4 v = row[c4];
        s += v.x * v.x;
        s += v.y * v.y;
        s += v.z * v.z;
        s += v.w * v.w;
        unsigned short t4[4] = {f2bf(v.x), f2bf(v.y), f2bf(v.z), f2bf(v.w)};
        *(uint2*)(wpl + (size_t)k * CPAD + c4 * 4) = *(const uint2*)t4;
    }
    ((float*)(out + OUTHALF + 262144 + 32768))[k] = s;     // exact w2
    unsigned short* rowp = wpl + (size_t)k * CPAD + 256;
    rowp[0] = f2bf(-0.5f * s);
    for (int j = 1; j < 64; ++j) rowp[j] = 0;
}

// ---- kernel B: MFMA approx scores + candidate collection + exact recheck ----
__global__ __launch_bounds__(256) void vq_main(const float* __restrict__ z,
                                               const float* __restrict__ w,
                                               float* __restrict__ out) {
    __shared__ uint4 ztb[128 * 9];          // 128 n-rows x 144 B (64c bf16 + pad)
    __shared__ unsigned rmink[128];
    __shared__ unsigned cnt[128];
    __shared__ unsigned candk[128 * CAP];
    __shared__ unsigned long long best[128];
    __shared__ unsigned short ovlist[128];
    __shared__ unsigned ovcnt;

    const int t = threadIdx.x;
    const int lane = t & 63;
    const int wid = t >> 6;
    const int n0 = blockIdx.x * 128;
    const int l15 = lane & 15;
    const int lq  = lane >> 4;

    const unsigned short* zpl = (const unsigned short*)out;
    const unsigned short* wpl = (const unsigned short*)(out + OUTHALF);
    const float* z2arr = (const float*)(out + OUTHALF + 262144);
    const float* w2arr = (const float*)(out + OUTHALF + 262144 + 32768);

    for (int i = t; i < 128; i += 256) {
        rmink[i] = 0xFF7FFFFFu;             // fkey(FLT_MAX)
        cnt[i] = 0;
        best[i] = ~0ull;
    }
    if (t == 0) ovcnt = 0;

    #pragma unroll 1
    for (int pass = 0; pass < 8; ++pass) {
        const int kbase = pass * 128 + wid * 32;
        f32x4 acc[2][8];
        #pragma unroll
        for (int kt = 0; kt < 2; ++kt)
            #pragma unroll
            for (int sub = 0; sub < 8; ++sub) acc[kt][sub] = 0.0f;

        #pragma unroll 1
        for (int chunk = 0; chunk < 5; ++chunk) {
            __syncthreads();
            #pragma unroll
            for (int i = 0; i < 4; ++i) {
                int id = i * 256 + t;
                int row = id >> 3, seg = id & 7;
                ztb[row * 9 + seg] =
                    *(const uint4*)(zpl + (size_t)(n0 + row) * CPAD + chunk * 64 + seg * 8);
            }
            __syncthreads();
            #pragma unroll
            for (int step = 0; step < 2; ++step) {
                const int cs = chunk * 64 + step * 32;
                bf16x8 afr[2];
                #pragma unroll
                for (int kt = 0; kt < 2; ++kt) {
                    int rowk = kbase + kt * 16 + l15;
                    afr[kt] = *(const bf16x8*)(wpl + (size_t)rowk * CPAD + cs + lq * 8);
                }
                #pragma unroll
                for (int sub = 0; sub < 8; ++sub) {
                    int n = sub * 16 + l15;
                    bf16x8 bfr = *(const bf16x8*)((const unsigned short*)ztb + n * 72 + step * 32 + lq * 8);
                    #pragma unroll
                    for (int kt = 0; kt < 2; ++kt)
                        acc[kt][sub] = __builtin_amdgcn_mfma_f32_16x16x32_bf16(
                            afr[kt], bfr, acc[kt][sub], 0, 0, 0);
                }
            }
        }
        // finalize pass (a): settle per-n running min
        #pragma unroll
        for (int sub = 0; sub < 8; ++sub) {
            int n = sub * 16 + l15;
            float m = 3.4e38f;
            #pragma unroll
            for (int kt = 0; kt < 2; ++kt)
                #pragma unroll
                for (int r = 0; r < 4; ++r) m = fminf(m, -2.0f * acc[kt][sub][r]);
            atomicMin(&rmink[n], fkey(m));
        }
        __syncthreads();
        // finalize pass (c): append all k within margin of settled min
        #pragma unroll
        for (int sub = 0; sub < 8; ++sub) {
            int n = sub * 16 + l15;
            float thr = finv(rmink[n]) + MARGIN;
            #pragma unroll
            for (int kt = 0; kt < 2; ++kt)
                #pragma unroll
                for (int r = 0; r < 4; ++r) {
                    float s = -2.0f * acc[kt][sub][r];
                    if (s <= thr) {
                        unsigned slot = atomicAdd(&cnt[n], 1u);
                        if (slot < CAP) candk[n * CAP + slot] = (unsigned)(kbase + kt * 16 + lq * 4 + r);
                    }
                }
        }
        __syncthreads();
    }

    // overflow list
    if (t < 128 && cnt[t] > CAP) {
        unsigned o = atomicAdd(&ovcnt, 1u);
        ovlist[o] = (unsigned short)t;
    }
    // exact recheck of candidates (reference chain: sequential-c fmaf, first-index ties)
    #pragma unroll 1
    for (int p = t; p < 128 * CAP; p += 256) {
        int nl = p / CAP, slot = p % CAP;
        unsigned c_ = cnt[nl];
        if (c_ > CAP || slot >= (int)c_) continue;
        unsigned k = candk[p];
        int n = n0 + nl;
        const float* zc = z + (size_t)(n >> 10) * 262144 + (n & 1023);
        const float* wr = w + (size_t)k * 256;
        float s = 0.0f;
        #pragma unroll 8
        for (int c = 0; c < 256; ++c) s = fmaf(zc[(size_t)c * 1024], wr[c], s);
        float d = fmaf(-2.0f, s, z2arr[n]) + w2arr[k];
        atomicMinU64(&best[nl], ((unsigned long long)__float_as_uint(d) << 32) | k);
    }
    __syncthreads();
    // rare fallback: full exact scan for overflowed n (one wave per n)
    for (unsigned o = wid; o < ovcnt; o += 4) {
        int nl = ovlist[o];
        int n = n0 + nl;
        const float* zc = z + (size_t)(n >> 10) * 262144 + (n & 1023);
        unsigned long long m = ~0ull;
        for (int kk = lane; kk < 1024; kk += 64) {
            const float* wr = w + (size_t)kk * 256;
            float s = 0.0f;
            #pragma unroll 8
            for (int c = 0; c < 256; ++c) s = fmaf(zc[(size_t)c * 1024], wr[c], s);
            float d = fmaf(-2.0f, s, z2arr[n]) + w2arr[kk];
            unsigned long long key = ((unsigned long long)__float_as_uint(d) << 32) | (unsigned)kk;
            m = (key < m) ? key : m;
        }
        #pragma unroll
        for (int sh = 1; sh <= 32; sh <<= 1) {
            unsigned long long o2 = __shfl_xor(m, sh, 64);
            m = (o2 < m) ? o2 : m;
        }
        if (lane == 0) atomicMinU64(&best[nl], m);
    }
    __syncthreads();
    if (t < 128) out[(size_t)2 * OUTHALF + n0 + t] = (float)(unsigned)(best[t] & 0xFFFFFFFFu);
}

// ---- kernel C: gather + write code/detached (round-5 proven epilogue) ----
__global__ __launch_bounds__(256) void epilogue(const float* __restrict__ z,
                                                const float* __restrict__ w,
                                                float* __restrict__ out) {
    const int t = threadIdx.x;
    const int n0 = blockIdx.x * 32;
    const int b = n0 >> 10, hw0 = n0 & 1023;
    const int n = t & 31;
    const int q = t >> 5;
    const int kn = (int)out[(size_t)2 * OUTHALF + n0 + n];
    const float* wrow = w + (size_t)kn * 256;
    const size_t obase = (size_t)b * 262144 + hw0;
    #pragma unroll
    for (int cc = 0; cc < 8; ++cc) {
        const int c0 = (q + cc * 8) * 4;
        const float4 cv = *(const float4*)(wrow + c0);
        const float cvf[4] = {cv.x, cv.y, cv.z, cv.w};
        #pragma unroll
        for (int u = 0; u < 4; ++u) {
            const size_t off = obase + (size_t)(c0 + u) * 1024 + n;
            const float zz = z[off];
            out[off] = cvf[u];
            out[OUTHALF + off] = (cvf[u] - zz) + zz;   // reference rounding chain
        }
    }
}

extern "C" void kernel_launch(void* const* d_in, const int* in_sizes, int n_in,
                              void* d_out, int out_size, void* d_ws, size_t ws_size,
                              hipStream_t stream) {
    const float* z = (const float*)d_in[0];
    const float* w = (const float*)d_in[1];
    float* out = (float*)d_out;
    prep_z  <<<512, 256, 0, stream>>>(z, out);
    prep_w  <<<4,   256, 0, stream>>>(w, out);
    vq_main <<<256, 256, 0, stream>>>(z, w, out);
    epilogue<<<1024, 256, 0, stream>>>(z, w, out);
}

// Round 10
// 127.443 us; speedup vs baseline: 2.1000x; 2.0857x over previous
//
#include <hip/hip_runtime.h>

#define OUTHALF 8388608
#define CPAD    320
#define ZSTR    328              // LDS z-tile row stride in shorts (656B: 16B-aligned, 2-way banks)
#define MARGIN  7.5e-4f
#define CAP     24

// d_out float-offset map (A=code region, B=detached region, C=idx; A/B overwritten by epilogue):
//   zplane bf16 [32768][320] : A+0         (5,242,880 floats)
//   wplane bf16 [1024][320]  : A+5,242,880 (163,840 floats)
//   z2 fp32 [32768]          : A+5,406,720
//   w2 fp32 [1024]           : A+5,439,488  (ends 5,440,512 < 8,388,608)
//   z_t fp32 [32768][256]    : B+0         (8,388,608 floats exactly)
#define WPL_OFF 5242880
#define Z2_OFF  5406720
#define W2_OFF  5439488

typedef float f32x4 __attribute__((ext_vector_type(4)));
typedef short bf16x8 __attribute__((ext_vector_type(8)));

__device__ __forceinline__ unsigned short f2bf(float x) {   // RNE fp32 -> bf16
    unsigned u = __float_as_uint(x);
    return (unsigned short)((u + 0x7FFFu + ((u >> 16) & 1u)) >> 16);
}
__device__ __forceinline__ unsigned fkey(float f) {         // order-preserving f32->u32
    unsigned b = __float_as_uint(f);
    return b ^ ((b & 0x80000000u) ? 0xFFFFFFFFu : 0x80000000u);
}
__device__ __forceinline__ float finv(unsigned k) {
    unsigned b = k ^ ((k & 0x80000000u) ? 0x80000000u : 0xFFFFFFFFu);
    return __uint_as_float(b);
}
__device__ __forceinline__ void atomicMinU64(unsigned long long* p, unsigned long long v) {
    unsigned long long cur = *p;
    while (v < cur) {
        unsigned long long old = atomicCAS(p, cur, v);
        if (old == cur) break;
        cur = old;
    }
}

// ---- kernel A1: zplane bf16 + z_t fp32 + exact z2 (z2 chain: sequential c, fmaf) ----
__global__ __launch_bounds__(256) void prep_z(const float* __restrict__ z,
                                              float* __restrict__ out) {
    __shared__ float tile[64][65];
    const int t = threadIdx.x;
    const int n0 = blockIdx.x * 64;
    const int b = n0 >> 10, hw0 = n0 & 1023;
    const float* zb = z + (size_t)b * 262144 + hw0;
    unsigned short* zpl = (unsigned short*)out;
    float* zt = out + OUTHALF;
    float z2a = 0.0f;

    for (int ch = 0; ch < 4; ++ch) {
        __syncthreads();
        #pragma unroll
        for (int r = 0; r < 16; ++r) {
            int c = r * 4 + (t >> 6);
            int nn = t & 63;
            tile[c][nn] = zb[(size_t)(ch * 64 + c) * 1024 + nn];
        }
        __syncthreads();
        #pragma unroll
        for (int i = 0; i < 2; ++i) {
            int id = i * 256 + t;
            int row = id >> 3, seg = id & 7;
            float f[8];
            unsigned short h[8];
            #pragma unroll
            for (int j = 0; j < 8; ++j) { f[j] = tile[seg * 8 + j][row]; h[j] = f2bf(f[j]); }
            *(uint4*)(zpl + (size_t)(n0 + row) * CPAD + ch * 64 + seg * 8) = *(const uint4*)h;
            *(float4*)(zt + (size_t)(n0 + row) * 256 + ch * 64 + seg * 8)     = *(const float4*)(f);
            *(float4*)(zt + (size_t)(n0 + row) * 256 + ch * 64 + seg * 8 + 4) = *(const float4*)(f + 4);
        }
        if (t < 64) {   // z2 partial for this chunk, ascending c (exact fp32 from LDS)
            #pragma unroll 8
            for (int c = 0; c < 64; ++c) { float v = tile[c][t]; z2a = fmaf(v, v, z2a); }
        }
    }
    if (t < 64) {
        (out + Z2_OFF)[n0 + t] = z2a;
        unsigned short* rowp = zpl + (size_t)(n0 + t) * CPAD + 256;
        rowp[0] = 0x3F80;                                  // bf16(1.0)
        #pragma unroll
        for (int j = 1; j < 64; ++j) rowp[j] = 0;
    }
}

// ---- kernel A2: wplane bf16 (slot256 = bf16(-w2/2)) + exact w2 ----
__global__ __launch_bounds__(256) void prep_w(const float* __restrict__ w,
                                              float* __restrict__ out) {
    const int k = blockIdx.x * 256 + threadIdx.x;
    if (k >= 1024) return;
    unsigned short* wpl = (unsigned short*)(out + WPL_OFF);
    const float4* row = (const float4*)(w + (size_t)k * 256);
    float s = 0.0f;
    #pragma unroll 4
    for (int c4 = 0; c4 < 64; ++c4) {
        float4 v = row[c4];
        s += v.x * v.x;
        s += v.y * v.y;
        s += v.z * v.z;
        s += v.w * v.w;
        unsigned short t4[4] = {f2bf(v.x), f2bf(v.y), f2bf(v.z), f2bf(v.w)};
        *(uint2*)(wpl + (size_t)k * CPAD + c4 * 4) = *(const uint2*)t4;
    }
    (out + W2_OFF)[k] = s;
    unsigned short* rowp = wpl + (size_t)k * CPAD + 256;
    rowp[0] = f2bf(-0.5f * s);
    #pragma unroll
    for (int j = 1; j < 64; ++j) rowp[j] = 0;
}

// ---- kernel B: MFMA scores + candidates + exact recheck (z_t-fed, queue-compacted) ----
__global__ __launch_bounds__(256) void vq_main(const float* __restrict__ w,
                                               float* __restrict__ out) {
    __shared__ unsigned short ztb[64 * ZSTR];       // 41,984 B, staged once
    __shared__ unsigned rmink[64];
    __shared__ unsigned cnt[64];
    __shared__ unsigned candk[64 * CAP];
    __shared__ unsigned long long best[64];
    __shared__ unsigned short qpk[64 * CAP];        // packed (nl<<10 | k)
    __shared__ unsigned short ovlist[64];
    __shared__ unsigned ovcnt, qcnt;

    const int t = threadIdx.x;
    const int lane = t & 63;
    const int wid = t >> 6;
    const int n0 = blockIdx.x * 64;
    const int l15 = lane & 15;
    const int lq  = lane >> 4;

    const unsigned short* zpl = (const unsigned short*)out;
    const unsigned short* wpl = (const unsigned short*)(out + WPL_OFF);
    const float* z2arr = out + Z2_OFF;
    const float* w2arr = out + W2_OFF;
    const float* zt = out + OUTHALF;

    for (int i = t; i < 64; i += 256) {
        rmink[i] = 0xFF7FFFFFu;                     // fkey(FLT_MAX)
        cnt[i] = 0;
        best[i] = ~0ull;
    }
    if (t == 0) { ovcnt = 0; qcnt = 0; }

    // stage the whole z-tile once (64 n x 320 c bf16)
    #pragma unroll
    for (int i = 0; i < 10; ++i) {
        int id = i * 256 + t;                       // 0..2559
        int row = id / 40, seg = id % 40;
        *(uint4*)&ztb[row * ZSTR + seg * 8] =
            *(const uint4*)(zpl + (size_t)(n0 + row) * CPAD + seg * 8);
    }
    __syncthreads();

    #pragma unroll 1
    for (int pass = 0; pass < 8; ++pass) {
        const int kbase = pass * 128 + wid * 32;
        f32x4 acc[2][4];
        #pragma unroll
        for (int kt = 0; kt < 2; ++kt)
            #pragma unroll
            for (int sub = 0; sub < 4; ++sub) acc[kt][sub] = 0.0f;

        const unsigned short* wrow0 = wpl + (size_t)(kbase + l15) * CPAD + lq * 8;
        const unsigned short* wrow1 = wrow0 + 16 * CPAD;
        bf16x8 a0 = *(const bf16x8*)wrow0;
        bf16x8 a1 = *(const bf16x8*)wrow1;
        #pragma unroll
        for (int step = 0; step < 10; ++step) {
            const int sn = (step < 9) ? step + 1 : 9;   // prefetch next step's A-frags
            bf16x8 na0 = *(const bf16x8*)(wrow0 + sn * 32);
            bf16x8 na1 = *(const bf16x8*)(wrow1 + sn * 32);
            const int cs = step * 32;
            #pragma unroll
            for (int sub = 0; sub < 4; ++sub) {
                const int n = sub * 16 + l15;
                bf16x8 bfr = *(const bf16x8*)&ztb[n * ZSTR + cs + lq * 8];
                acc[0][sub] = __builtin_amdgcn_mfma_f32_16x16x32_bf16(a0, bfr, acc[0][sub], 0, 0, 0);
                acc[1][sub] = __builtin_amdgcn_mfma_f32_16x16x32_bf16(a1, bfr, acc[1][sub], 0, 0, 0);
            }
            a0 = na0; a1 = na1;
        }
        // settle per-n running min
        #pragma unroll
        for (int sub = 0; sub < 4; ++sub) {
            const int n = sub * 16 + l15;
            float m = 3.4e38f;
            #pragma unroll
            for (int kt = 0; kt < 2; ++kt)
                #pragma unroll
                for (int r = 0; r < 4; ++r) m = fminf(m, -2.0f * acc[kt][sub][r]);
            atomicMin(&rmink[n], fkey(m));
        }
        __syncthreads();
        // append candidates within margin of settled min
        #pragma unroll
        for (int sub = 0; sub < 4; ++sub) {
            const int n = sub * 16 + l15;
            const float thr = finv(rmink[n]) + MARGIN;
            #pragma unroll
            for (int kt = 0; kt < 2; ++kt)
                #pragma unroll
                for (int r = 0; r < 4; ++r) {
                    const float s = -2.0f * acc[kt][sub][r];
                    if (s <= thr) {
                        unsigned slot = atomicAdd(&cnt[n], 1u);
                        if (slot < CAP)
                            candk[n * CAP + slot] = (unsigned)(kbase + kt * 16 + lq * 4 + r);
                    }
                }
        }
        __syncthreads();
    }

    // compact (n,k) work queue; overflowed n go to full-scan fallback
    if (t < 64) {
        const unsigned c_ = cnt[t];
        if (c_ > CAP) {
            unsigned o = atomicAdd(&ovcnt, 1u);
            ovlist[o] = (unsigned short)t;
        } else if (c_ > 0) {
            unsigned base = atomicAdd(&qcnt, c_);
            for (unsigned s = 0; s < c_; ++s)
                qpk[base + s] = (unsigned short)((t << 10) | candk[t * CAP + s]);
        }
    }
    __syncthreads();

    // exact recheck (reference chain: sequential-c fmaf on exact fp32; first-index ties via u64)
    const unsigned M = qcnt;
    for (unsigned p = t; p < M; p += 256) {
        const unsigned e = qpk[p];
        const int nl = e >> 10, k = e & 1023;
        const float* zr = zt + (size_t)(n0 + nl) * 256;
        const float* wr = w + (size_t)k * 256;
        float s = 0.0f;
        #pragma unroll 8
        for (int c = 0; c < 256; ++c) s = fmaf(zr[c], wr[c], s);
        const float d = fmaf(-2.0f, s, z2arr[n0 + nl]) + w2arr[k];
        atomicMinU64(&best[nl], ((unsigned long long)__float_as_uint(d) << 32) | (unsigned)k);
    }
    __syncthreads();
    // rare fallback: full exact scan for overflowed n (one wave per n)
    for (unsigned o = wid; o < ovcnt; o += 4) {
        const int nl = ovlist[o];
        const float* zr = zt + (size_t)(n0 + nl) * 256;
        unsigned long long m = ~0ull;
        for (int kk = lane; kk < 1024; kk += 64) {
            const float* wr = w + (size_t)kk * 256;
            float s = 0.0f;
            #pragma unroll 8
            for (int c = 0; c < 256; ++c) s = fmaf(zr[c], wr[c], s);
            const float d = fmaf(-2.0f, s, z2arr[n0 + nl]) + w2arr[kk];
            const unsigned long long key =
                ((unsigned long long)__float_as_uint(d) << 32) | (unsigned)kk;
            m = (key < m) ? key : m;
        }
        #pragma unroll
        for (int sh = 1; sh <= 32; sh <<= 1) {
            const unsigned long long o2 = __shfl_xor(m, sh, 64);
            m = (o2 < m) ? o2 : m;
        }
        if (lane == 0) atomicMinU64(&best[nl], m);
    }
    __syncthreads();
    if (t < 64) out[(size_t)2 * OUTHALF + n0 + t] = (float)(unsigned)(best[t] & 0xFFFFFFFFu);
}

// ---- kernel C: gather + write code/detached (proven epilogue, reference rounding chain) ----
__global__ __launch_bounds__(256) void epilogue(const float* __restrict__ z,
                                                const float* __restrict__ w,
                                                float* __restrict__ out) {
    const int t = threadIdx.x;
    const int n0 = blockIdx.x * 32;
    const int b = n0 >> 10, hw0 = n0 & 1023;
    const int n = t & 31;
    const int q = t >> 5;
    const int kn = (int)out[(size_t)2 * OUTHALF + n0 + n];
    const float* wrow = w + (size_t)kn * 256;
    const size_t obase = (size_t)b * 262144 + hw0;
    #pragma unroll
    for (int cc = 0; cc < 8; ++cc) {
        const int c0 = (q + cc * 8) * 4;
        const float4 cv = *(const float4*)(wrow + c0);
        const float cvf[4] = {cv.x, cv.y, cv.z, cv.w};
        #pragma unroll
        for (int u = 0; u < 4; ++u) {
            const size_t off = obase + (size_t)(c0 + u) * 1024 + n;
            const float zz = z[off];
            out[off] = cvf[u];
            out[OUTHALF + off] = (cvf[u] - zz) + zz;   // reference rounding chain
        }
    }
}

extern "C" void kernel_launch(void* const* d_in, const int* in_sizes, int n_in,
                              void* d_out, int out_size, void* d_ws, size_t ws_size,
                              hipStream_t stream) {
    const float* z = (const float*)d_in[0];
    const float* w = (const float*)d_in[1];
    float* out = (float*)d_out;
    prep_z  <<<512,  256, 0, stream>>>(z, out);
    prep_w  <<<4,    256, 0, stream>>>(w, out);
    vq_main <<<512,  256, 0, stream>>>(w, out);
    epilogue<<<1024, 256, 0, stream>>>(z, w, out);
}

// Round 11
// 117.675 us; speedup vs baseline: 2.2744x; 1.0830x over previous
//
#include <hip/hip_runtime.h>

#define OUTHALF 8388608
#define CPAD    320
#define ZSTR    328              // bf16 z-tile row stride (shorts); 656B rows -> 2-way banks max
#define Z32S    260              // fp32 z-row stride (floats); 1040B rows, 16B-aligned, 4-way banks max
#define MARGIN  7.5e-4f
#define CAP     24

// d_out float-offset map (A=code region, B=detached region; both overwritten at the end):
//   zplane bf16 [32768][320] : A+0
//   wplane bf16 [1024][320]  : A+5,242,880
//   z2 fp32 [32768]          : A+5,406,720
//   w2 fp32 [1024]           : A+5,439,488
//   z_t fp32 [32768][256]    : B+0  (exactly 8,388,608 floats)
#define WPL_OFF 5242880
#define Z2_OFF  5406720
#define W2_OFF  5439488

typedef float f32x4 __attribute__((ext_vector_type(4)));
typedef short bf16x8 __attribute__((ext_vector_type(8)));

__device__ __forceinline__ unsigned short f2bf(float x) {   // RNE fp32 -> bf16
    unsigned u = __float_as_uint(x);
    return (unsigned short)((u + 0x7FFFu + ((u >> 16) & 1u)) >> 16);
}
__device__ __forceinline__ unsigned fkey(float f) {         // order-preserving f32->u32
    unsigned b = __float_as_uint(f);
    return b ^ ((b & 0x80000000u) ? 0xFFFFFFFFu : 0x80000000u);
}
__device__ __forceinline__ float finv(unsigned k) {
    unsigned b = k ^ ((k & 0x80000000u) ? 0x80000000u : 0xFFFFFFFFu);
    return __uint_as_float(b);
}
__device__ __forceinline__ void atomicMinU64(unsigned long long* p, unsigned long long v) {
    unsigned long long cur = *p;
    while (v < cur) {
        unsigned long long old = atomicCAS(p, cur, v);
        if (old == cur) break;
        cur = old;
    }
}

// ---- kernel A1: zplane bf16 + z_t fp32 + exact z2 (sequential-c fmaf chain) ----
__global__ __launch_bounds__(256) void prep_z(const float* __restrict__ z,
                                              float* __restrict__ out) {
    __shared__ float tile[64][65];
    const int t = threadIdx.x;
    const int n0 = blockIdx.x * 64;
    const int b = n0 >> 10, hw0 = n0 & 1023;
    const float* zb = z + (size_t)b * 262144 + hw0;
    unsigned short* zpl = (unsigned short*)out;
    float* zt = out + OUTHALF;
    float z2a = 0.0f;

    for (int ch = 0; ch < 4; ++ch) {
        __syncthreads();
        #pragma unroll
        for (int r = 0; r < 16; ++r) {
            int c = r * 4 + (t >> 6);
            int nn = t & 63;
            tile[c][nn] = zb[(size_t)(ch * 64 + c) * 1024 + nn];
        }
        __syncthreads();
        #pragma unroll
        for (int i = 0; i < 2; ++i) {
            int id = i * 256 + t;
            int row = id >> 3, seg = id & 7;
            float f[8];
            unsigned short h[8];
            #pragma unroll
            for (int j = 0; j < 8; ++j) { f[j] = tile[seg * 8 + j][row]; h[j] = f2bf(f[j]); }
            *(uint4*)(zpl + (size_t)(n0 + row) * CPAD + ch * 64 + seg * 8) = *(const uint4*)h;
            *(float4*)(zt + (size_t)(n0 + row) * 256 + ch * 64 + seg * 8)     = *(const float4*)(f);
            *(float4*)(zt + (size_t)(n0 + row) * 256 + ch * 64 + seg * 8 + 4) = *(const float4*)(f + 4);
        }
        if (t < 64) {   // z2 partial, ascending c, exact fp32 from LDS
            #pragma unroll 8
            for (int c = 0; c < 64; ++c) { float v = tile[c][t]; z2a = fmaf(v, v, z2a); }
        }
    }
    if (t < 64) {
        (out + Z2_OFF)[n0 + t] = z2a;
        unsigned short* rowp = zpl + (size_t)(n0 + t) * CPAD + 256;
        rowp[0] = 0x3F80;                                  // bf16(1.0)
        #pragma unroll
        for (int j = 1; j < 64; ++j) rowp[j] = 0;
    }
}

// ---- kernel A2: wplane bf16 (slot256 = bf16(-w2/2)) + exact w2 ----
__global__ __launch_bounds__(256) void prep_w(const float* __restrict__ w,
                                              float* __restrict__ out) {
    const int k = blockIdx.x * 256 + threadIdx.x;
    if (k >= 1024) return;
    unsigned short* wpl = (unsigned short*)(out + WPL_OFF);
    const float4* row = (const float4*)(w + (size_t)k * 256);
    float s = 0.0f;
    #pragma unroll 4
    for (int c4 = 0; c4 < 64; ++c4) {
        float4 v = row[c4];
        s += v.x * v.x;
        s += v.y * v.y;
        s += v.z * v.z;
        s += v.w * v.w;
        unsigned short t4[4] = {f2bf(v.x), f2bf(v.y), f2bf(v.z), f2bf(v.w)};
        *(uint2*)(wpl + (size_t)k * CPAD + c4 * 4) = *(const uint2*)t4;
    }
    (out + W2_OFF)[k] = s;
    unsigned short* rowp = wpl + (size_t)k * CPAD + 256;
    rowp[0] = f2bf(-0.5f * s);
    #pragma unroll
    for (int j = 1; j < 64; ++j) rowp[j] = 0;
}

// ---- kernel B: MFMA scores + candidates + LDS-fed exact recheck (512-thread blocks) ----
__global__ __launch_bounds__(512) void vq_main(const float* __restrict__ w,
                                               float* __restrict__ out) {
    // union buffer: bf16 z-tile (41,984 B) during MFMA passes, fp32 z rows (66,560 B) after
    __shared__ __align__(16) unsigned char zraw[64 * Z32S * 4];
    __shared__ unsigned rmink[64];
    __shared__ unsigned cnt[64];
    __shared__ unsigned candk[64 * CAP];
    __shared__ unsigned long long best[64];
    __shared__ unsigned short qpk[64 * CAP];        // packed (nl<<10 | k), nl<64 -> fits u16
    __shared__ unsigned short ovlist[64];
    __shared__ unsigned ovcnt, qcnt;

    const int t = threadIdx.x;
    const int lane = t & 63;
    const int wid = t >> 6;                          // 0..7
    const int n0 = blockIdx.x * 64;
    const int l15 = lane & 15;
    const int lq  = lane >> 4;

    const unsigned short* zpl = (const unsigned short*)out;
    const unsigned short* wpl = (const unsigned short*)(out + WPL_OFF);
    const float* z2arr = out + Z2_OFF;
    const float* w2arr = out + W2_OFF;
    const float* zt = out + OUTHALF;

    unsigned short* ztb = (unsigned short*)zraw;
    float (*z32)[Z32S] = (float (*)[Z32S])zraw;

    if (t < 64) {
        rmink[t] = 0xFF7FFFFFu;                      // fkey(FLT_MAX)
        cnt[t] = 0;
        best[t] = ~0ull;
    }
    if (t == 0) { ovcnt = 0; qcnt = 0; }

    // stage bf16 z-tile once (64 n x 320 c)
    #pragma unroll
    for (int i = 0; i < 5; ++i) {
        int id = i * 512 + t;                        // 0..2559
        int row = id / 40, seg = id % 40;
        *(uint4*)&ztb[row * ZSTR + seg * 8] =
            *(const uint4*)(zpl + (size_t)(n0 + row) * CPAD + seg * 8);
    }
    __syncthreads();

    #pragma unroll 1
    for (int pass = 0; pass < 4; ++pass) {
        const int kbase = pass * 256 + wid * 32;
        f32x4 acc[2][4];
        #pragma unroll
        for (int kt = 0; kt < 2; ++kt)
            #pragma unroll
            for (int sub = 0; sub < 4; ++sub) acc[kt][sub] = 0.0f;

        const unsigned short* wrow0 = wpl + (size_t)(kbase + l15) * CPAD + lq * 8;
        const unsigned short* wrow1 = wrow0 + 16 * CPAD;
        bf16x8 a0 = *(const bf16x8*)wrow0;
        bf16x8 a1 = *(const bf16x8*)wrow1;
        #pragma unroll
        for (int step = 0; step < 10; ++step) {
            const int sn = (step < 9) ? step + 1 : 9;   // prefetch next step's A-frags
            bf16x8 na0 = *(const bf16x8*)(wrow0 + sn * 32);
            bf16x8 na1 = *(const bf16x8*)(wrow1 + sn * 32);
            const int cs = step * 32;
            #pragma unroll
            for (int sub = 0; sub < 4; ++sub) {
                const int n = sub * 16 + l15;
                bf16x8 bfr = *(const bf16x8*)&ztb[n * ZSTR + cs + lq * 8];
                acc[0][sub] = __builtin_amdgcn_mfma_f32_16x16x32_bf16(a0, bfr, acc[0][sub], 0, 0, 0);
                acc[1][sub] = __builtin_amdgcn_mfma_f32_16x16x32_bf16(a1, bfr, acc[1][sub], 0, 0, 0);
            }
            a0 = na0; a1 = na1;
        }
        // settle per-n running min
        #pragma unroll
        for (int sub = 0; sub < 4; ++sub) {
            const int n = sub * 16 + l15;
            float m = 3.4e38f;
            #pragma unroll
            for (int kt = 0; kt < 2; ++kt)
                #pragma unroll
                for (int r = 0; r < 4; ++r) m = fminf(m, -2.0f * acc[kt][sub][r]);
            atomicMin(&rmink[n], fkey(m));
        }
        __syncthreads();
        // append candidates within margin of settled min
        #pragma unroll
        for (int sub = 0; sub < 4; ++sub) {
            const int n = sub * 16 + l15;
            const float thr = finv(rmink[n]) + MARGIN;
            #pragma unroll
            for (int kt = 0; kt < 2; ++kt)
                #pragma unroll
                for (int r = 0; r < 4; ++r) {
                    const float s = -2.0f * acc[kt][sub][r];
                    if (s <= thr) {
                        unsigned slot = atomicAdd(&cnt[n], 1u);
                        if (slot < CAP)
                            candk[n * CAP + slot] = (unsigned)(kbase + kt * 16 + lq * 4 + r);
                    }
                }
        }
        __syncthreads();
    }

    // overwrite union with exact fp32 z rows (from z_t, coalesced)
    #pragma unroll
    for (int i = 0; i < 8; ++i) {
        int id = i * 512 + t;                        // 0..4095
        int row = id >> 6, seg = id & 63;
        float4 v = *(const float4*)(zt + (size_t)(n0 + row) * 256 + seg * 4);
        *(float4*)&z32[row][seg * 4] = v;
    }
    // compact (n,k) work queue; overflowed n go to full-scan fallback
    if (t < 64) {
        const unsigned c_ = cnt[t];
        if (c_ > CAP) {
            unsigned o = atomicAdd(&ovcnt, 1u);
            ovlist[o] = (unsigned short)t;
        } else if (c_ > 0) {
            unsigned base = atomicAdd(&qcnt, c_);
            for (unsigned s = 0; s < c_; ++s)
                qpk[base + s] = (unsigned short)((t << 10) | candk[t * CAP + s]);
        }
    }
    __syncthreads();

    // exact recheck (reference chain: sequential-c fmaf on exact fp32; first-index ties via u64)
    const unsigned M = qcnt;
    for (unsigned p = t; p < M; p += 512) {
        const unsigned e = qpk[p];
        const int nl = e >> 10, k = e & 1023;
        const float* zr = z32[nl];
        const float* wr = w + (size_t)k * 256;
        float s = 0.0f;
        #pragma unroll 8
        for (int c = 0; c < 256; ++c) s = fmaf(zr[c], wr[c], s);
        const float d = fmaf(-2.0f, s, z2arr[n0 + nl]) + w2arr[k];
        atomicMinU64(&best[nl], ((unsigned long long)__float_as_uint(d) << 32) | (unsigned)k);
    }
    __syncthreads();
    // rare fallback: full exact scan for overflowed n (one wave per n)
    for (unsigned o = wid; o < ovcnt; o += 8) {
        const int nl = ovlist[o];
        const float* zr = z32[nl];
        unsigned long long m = ~0ull;
        for (int kk = lane; kk < 1024; kk += 64) {
            const float* wr = w + (size_t)kk * 256;
            float s = 0.0f;
            #pragma unroll 8
            for (int c = 0; c < 256; ++c) s = fmaf(zr[c], wr[c], s);
            const float d = fmaf(-2.0f, s, z2arr[n0 + nl]) + w2arr[kk];
            const unsigned long long key =
                ((unsigned long long)__float_as_uint(d) << 32) | (unsigned)kk;
            m = (key < m) ? key : m;
        }
        #pragma unroll
        for (int sh = 1; sh <= 32; sh <<= 1) {
            const unsigned long long o2 = __shfl_xor(m, sh, 64);
            m = (o2 < m) ? o2 : m;
        }
        if (lane == 0) atomicMinU64(&best[nl], m);
    }
    __syncthreads();
    if (t < 64) out[(size_t)2 * OUTHALF + n0 + t] = (float)(unsigned)(best[t] & 0xFFFFFFFFull);
}

// ---- kernel C: gather + write code/detached (proven epilogue, reference rounding chain) ----
__global__ __launch_bounds__(256) void epilogue(const float* __restrict__ z,
                                                const float* __restrict__ w,
                                                float* __restrict__ out) {
    const int t = threadIdx.x;
    const int n0 = blockIdx.x * 32;
    const int b = n0 >> 10, hw0 = n0 & 1023;
    const int n = t & 31;
    const int q = t >> 5;
    const int kn = (int)out[(size_t)2 * OUTHALF + n0 + n];
    const float* wrow = w + (size_t)kn * 256;
    const size_t obase = (size_t)b * 262144 + hw0;
    #pragma unroll
    for (int cc = 0; cc < 8; ++cc) {
        const int c0 = (q + cc * 8) * 4;
        const float4 cv = *(const float4*)(wrow + c0);
        const float cvf[4] = {cv.x, cv.y, cv.z, cv.w};
        #pragma unroll
        for (int u = 0; u < 4; ++u) {
            const size_t off = obase + (size_t)(c0 + u) * 1024 + n;
            const float zz = z[off];
            out[off] = cvf[u];
            out[OUTHALF + off] = (cvf[u] - zz) + zz;   // reference rounding chain
        }
    }
}

extern "C" void kernel_launch(void* const* d_in, const int* in_sizes, int n_in,
                              void* d_out, int out_size, void* d_ws, size_t ws_size,
                              hipStream_t stream) {
    const float* z = (const float*)d_in[0];
    const float* w = (const float*)d_in[1];
    float* out = (float*)d_out;
    prep_z  <<<512,  256, 0, stream>>>(z, out);
    prep_w  <<<4,    256, 0, stream>>>(w, out);
    vq_main <<<512,  512, 0, stream>>>(w, out);
    epilogue<<<1024, 256, 0, stream>>>(z, w, out);
}